// Round 2
// baseline (6564.400 us; speedup 1.0000x reference)
//
#include <hip/hip_runtime.h>
#include <hip/hip_bf16.h>

#define NND 50000
#define NE 800000
#define NM 2
#define INF 256
#define NH 4
#define HDIM 256
#define SHID 128
#define SLOPE 0.2f

typedef unsigned short u16;

__device__ __forceinline__ float us2f(u16 u) {
  union { unsigned int i; float f; } v; v.i = ((unsigned int)u) << 16; return v.f;
}
__device__ __forceinline__ u16 f2us(float f) {
  union { float f; unsigned int i; } v; v.f = f;
  unsigned int r = v.i + 0x7FFFu + ((v.i >> 16) & 1u);
  return (u16)(r >> 16);
}

template<int BF> __device__ __forceinline__ float ldf(const void* p, size_t i) {
  return BF ? us2f(((const u16*)p)[i]) : ((const float*)p)[i];
}

// k0: detect float dtype of inputs. bf16 -> flag=1, f32 -> flag=0.
// For bf16 data every u16 has exponent field ~[114,129]; for f32 data the
// even-index u16s are low mantissa bits (uniform) -> only ~58% in range.
__global__ void k0_detect(const u16* __restrict__ h, int* __restrict__ flag) {
  if (threadIdx.x == 0 && blockIdx.x == 0) {
    int hits = 0;
    for (int i = 0; i < 256; ++i) {
      int e = (h[i] >> 7) & 0xFF;
      if (e >= 100 && e <= 140) hits++;
    }
    *flag = (hits >= 200) ? 1 : 0;
  }
}

// K1: feat = h @ W[m] (f32 accum, bf16 out) + el/er wave reductions.
// Block = 256 threads = 256 output columns; 16 nodes per block.
template<int BF>
__global__ __launch_bounds__(256) void k1_gemm(
    const int* __restrict__ flag,
    const void* __restrict__ h, const void* __restrict__ W,
    const void* __restrict__ al, const void* __restrict__ ar,
    u16* __restrict__ feat, float* __restrict__ el, float* __restrict__ er,
    int m)
{
  if (*flag != BF) return;
  const int t = threadIdx.x;
  const int n0 = blockIdx.x * 16;
  const size_t wbase = (size_t)m * INF * HDIM;
  float acc[16];
#pragma unroll
  for (int i = 0; i < 16; ++i) acc[i] = 0.f;
  for (int k = 0; k < INF; ++k) {
    float w = ldf<BF>(W, wbase + (size_t)k * HDIM + t);
#pragma unroll
    for (int nn = 0; nn < 16; ++nn)
      acc[nn] = fmaf(ldf<BF>(h, (size_t)(n0 + nn) * INF + k), w, acc[nn]);
  }
  const int lane = t & 63;
  const int head = t >> 6;   // wave index == head (t = head*64 + d)
  const float alv = ldf<BF>(al, (size_t)m * HDIM + t);
  const float arv = ldf<BF>(ar, (size_t)m * HDIM + t);
#pragma unroll
  for (int nn = 0; nn < 16; ++nn) {
    float f = acc[nn];
    feat[(size_t)(n0 + nn) * HDIM + t] = f2us(f);
    float cl = f * alv;
    float cr = f * arv;
#pragma unroll
    for (int o = 32; o; o >>= 1) {
      cl += __shfl_xor(cl, o, 64);
      cr += __shfl_xor(cr, o, 64);
    }
    if (lane == 0) {
      el[(n0 + nn) * NH + head] = cl;
      er[(n0 + nn) * NH + head] = cr;
    }
  }
}

// K2: den[d,h] = sum_{e: dst=d} exp(leaky_relu(el[s]+er[d]))
// (no max-subtraction: softmax is shift-invariant; |e| <~ 10 so f32 exp safe)
__global__ __launch_bounds__(256) void k2_den(
    const int* __restrict__ src, const int* __restrict__ dst,
    const float* __restrict__ el, const float* __restrict__ er,
    float* __restrict__ den)
{
  int e = blockIdx.x * 256 + threadIdx.x;
  if (e >= NE) return;
  int s = src[e], d = dst[e];
  const float4 a = *(const float4*)(el + s * 4);
  const float4 b = *(const float4*)(er + d * 4);
  float x;
  x = a.x + b.x; x = x > 0.f ? x : SLOPE * x; unsafeAtomicAdd(den + d * 4 + 0, expf(x));
  x = a.y + b.y; x = x > 0.f ? x : SLOPE * x; unsafeAtomicAdd(den + d * 4 + 1, expf(x));
  x = a.z + b.z; x = x > 0.f ? x : SLOPE * x; unsafeAtomicAdd(den + d * 4 + 2, expf(x));
  x = a.w + b.w; x = x > 0.f ? x : SLOPE * x; unsafeAtomicAdd(den + d * 4 + 3, expf(x));
}

// K3: rst[d,:] += alpha * feat[s,:] -- one wave per edge, lane covers 4 feats.
__global__ __launch_bounds__(256) void k3_agg(
    const int* __restrict__ src, const int* __restrict__ dst,
    const float* __restrict__ el, const float* __restrict__ er,
    const float* __restrict__ den, const u16* __restrict__ feat,
    float* __restrict__ rst)
{
  const int lane = threadIdx.x & 63;
  const int h = lane >> 4;                       // head of this lane's 4 feats
  int wid = (blockIdx.x * blockDim.x + threadIdx.x) >> 6;
  const int nw = (gridDim.x * blockDim.x) >> 6;
  for (int e = wid; e < NE; e += nw) {
    int s = src[e], d = dst[e];
    float x = el[s * 4 + h] + er[d * 4 + h];
    x = x > 0.f ? x : SLOPE * x;
    float alpha = expf(x) / fmaxf(den[d * 4 + h], 1e-9f);
    const ushort4 f4 = *(const ushort4*)(feat + (size_t)s * HDIM + lane * 4);
    float* rp = rst + (size_t)d * HDIM + lane * 4;
    unsafeAtomicAdd(rp + 0, alpha * us2f(f4.x));
    unsafeAtomicAdd(rp + 1, alpha * us2f(f4.y));
    unsafeAtomicAdd(rp + 2, alpha * us2f(f4.z));
    unsafeAtomicAdd(rp + 3, alpha * us2f(f4.w));
  }
}

// K4: z = elu(rst) (store: m==0 -> d_out in OUT dtype, m==1 -> z1 bf16),
// plus semantic score: wsum[m] += sum_n sum_j tanh(z[n,:].w1[:,j]+b1[j])*w2[j]
template<int BF>
__global__ __launch_bounds__(256) void k4_sem(
    const int* __restrict__ flag,
    const float* __restrict__ rst, const void* __restrict__ w1,
    const void* __restrict__ b1, const void* __restrict__ w2,
    void* __restrict__ zout, u16* __restrict__ z1,
    float* __restrict__ wsum, int midx)
{
  if (*flag != BF) return;
  __shared__ float zl[2][HDIM];
  __shared__ float red[4];
  const int t = threadIdx.x;
  const int half = t >> 7;          // which node of the pair
  const int jj = t & 127;           // hidden unit
  const float b1f = ldf<BF>(b1, jj);
  const float w2f = ldf<BF>(w2, jj);
  float local = 0.f;
  for (int pp = 0; pp < 4; ++pp) {
    const int nbase = blockIdx.x * 8 + pp * 2;
    __syncthreads();                // protect zl from previous iter's readers
#pragma unroll
    for (int j = 0; j < 2; ++j) {
      const size_t idx = (size_t)(nbase + j) * HDIM + t;
      float v = rst[idx];
      v = v > 0.f ? v : (expf(v) - 1.f);   // elu
      if (midx == 0) {
        if (BF) ((u16*)zout)[idx] = f2us(v);
        else    ((float*)zout)[idx] = v;
      } else {
        z1[idx] = f2us(v);
      }
      zl[j][t] = v;
    }
    __syncthreads();
    float acc = 0.f;
    const float* zr = zl[half];
    for (int k = 0; k < HDIM; ++k)
      acc = fmaf(zr[k], ldf<BF>(w1, (size_t)k * SHID + jj), acc);
    local += tanhf(acc + b1f) * w2f;
  }
#pragma unroll
  for (int o = 32; o; o >>= 1) local += __shfl_xor(local, o, 64);
  const int lane = t & 63, wv = t >> 6;
  if (lane == 0) red[wv] = local;
  __syncthreads();
  if (t == 0) unsafeAtomicAdd(wsum + midx, red[0] + red[1] + red[2] + red[3]);
}

// K5: beta = softmax(wsum/N over m); out = b0*z0 + b1*z1 (z0 in d_out, in-place)
template<int BF>
__global__ __launch_bounds__(256) void k5_out(
    const int* __restrict__ flag,
    void* __restrict__ out, const u16* __restrict__ z1,
    const float* __restrict__ wsum)
{
  if (*flag != BF) return;
  const int i = blockIdx.x * 256 + threadIdx.x;   // group of 4 features
  float w0 = wsum[0] * (1.0f / NND);
  float w1v = wsum[1] * (1.0f / NND);
  float mx = fmaxf(w0, w1v);
  float e0 = expf(w0 - mx), e1 = expf(w1v - mx);
  float inv = 1.f / (e0 + e1);
  float b0 = e0 * inv, b1 = e1 * inv;
  ushort4 zb = ((const ushort4*)z1)[i];
  if (BF) {
    ushort4 a = ((const ushort4*)out)[i];
    ushort4 r;
    r.x = f2us(b0 * us2f(a.x) + b1 * us2f(zb.x));
    r.y = f2us(b0 * us2f(a.y) + b1 * us2f(zb.y));
    r.z = f2us(b0 * us2f(a.z) + b1 * us2f(zb.z));
    r.w = f2us(b0 * us2f(a.w) + b1 * us2f(zb.w));
    ((ushort4*)out)[i] = r;
  } else {
    float4 a = ((const float4*)out)[i];
    float4 r;
    r.x = b0 * a.x + b1 * us2f(zb.x);
    r.y = b0 * a.y + b1 * us2f(zb.y);
    r.z = b0 * a.z + b1 * us2f(zb.z);
    r.w = b0 * a.w + b1 * us2f(zb.w);
    ((float4*)out)[i] = r;
  }
}

extern "C" void kernel_launch(void* const* d_in, const int* in_sizes, int n_in,
                              void* d_out, int out_size, void* d_ws, size_t ws_size,
                              hipStream_t stream)
{
  const int* src = (const int*)d_in[1];
  const int* dst = (const int*)d_in[2];

  // workspace layout (bytes)
  char* wsb = (char*)d_ws;
  float* rst  = (float*)(wsb);               // 50000*256*4 = 51,200,000
  u16*   feat = (u16*)(wsb + 51200000);      // 50000*256*2 = 25,600,000 (z1 aliases)
  float* el   = (float*)(wsb + 76800000);    // 800,000
  float* er   = (float*)(wsb + 77600000);    // 800,000
  float* den  = (float*)(wsb + 78400000);    // 800,000
  float* wsum = (float*)(wsb + 79200000);    // 8
  int*   flag = (int*)(wsb + 79200008);      // 4
  const size_t NEED = 79200016;
  if (ws_size < NEED) {
    // diagnostic sentinel: huge FINITE values (0x7F pattern ~ 3.4e38)
    hipMemsetAsync(d_out, 0x7F, (size_t)out_size * 2, stream);
    return;
  }
  u16* z1 = feat;   // alias: feat dead after k3(m=1), z1 written by k4(m=1)

  k0_detect<<<1, 64, 0, stream>>>((const u16*)d_in[0], flag);
  hipMemsetAsync(wsum, 0, 2 * sizeof(float), stream);
  for (int m = 0; m < NM; ++m) {
    hipMemsetAsync(den, 0, (size_t)NND * NH * sizeof(float), stream);
    hipMemsetAsync(rst, 0, (size_t)NND * HDIM * sizeof(float), stream);
    k1_gemm<0><<<NND / 16, 256, 0, stream>>>(flag, d_in[0], d_in[3], d_in[4], d_in[5], feat, el, er, m);
    k1_gemm<1><<<NND / 16, 256, 0, stream>>>(flag, d_in[0], d_in[3], d_in[4], d_in[5], feat, el, er, m);
    k2_den<<<NE / 256, 256, 0, stream>>>(src + (size_t)m * NE, dst + (size_t)m * NE, el, er, den);
    k3_agg<<<4096, 256, 0, stream>>>(src + (size_t)m * NE, dst + (size_t)m * NE, el, er, den, feat, rst);
    k4_sem<0><<<NND / 8, 256, 0, stream>>>(flag, rst, d_in[6], d_in[7], d_in[8], d_out, z1, wsum, m);
    k4_sem<1><<<NND / 8, 256, 0, stream>>>(flag, rst, d_in[6], d_in[7], d_in[8], d_out, z1, wsum, m);
  }
  k5_out<0><<<(NND * HDIM / 4) / 256, 256, 0, stream>>>(flag, d_out, z1, wsum);
  k5_out<1><<<(NND * HDIM / 4) / 256, 256, 0, stream>>>(flag, d_out, z1, wsum);
}

// Round 3
// 1545.064 us; speedup vs baseline: 4.2486x; 4.2486x over previous
//
#include <hip/hip_runtime.h>
#include <hip/hip_bf16.h>

#define NND 50000
#define NE 800000
#define NM 2
#define INF 256
#define NH 4
#define HDIM 256
#define SHID 128
#define SLOPE 0.2f

typedef unsigned short u16;

__device__ __forceinline__ float us2f(u16 u) {
  union { unsigned int i; float f; } v; v.i = ((unsigned int)u) << 16; return v.f;
}
__device__ __forceinline__ u16 f2us(float f) {
  union { float f; unsigned int i; } v; v.f = f;
  unsigned int r = v.i + 0x7FFFu + ((v.i >> 16) & 1u);
  return (u16)(r >> 16);
}

template<int BF> __device__ __forceinline__ float ldf(const void* p, size_t i) {
  return BF ? us2f(((const u16*)p)[i]) : ((const float*)p)[i];
}

// k0: detect float dtype of inputs. bf16 -> flag=1, f32 -> flag=0.
__global__ void k0_detect(const u16* __restrict__ h, int* __restrict__ flag) {
  if (threadIdx.x == 0 && blockIdx.x == 0) {
    int hits = 0;
    for (int i = 0; i < 256; ++i) {
      int e = (h[i] >> 7) & 0xFF;
      if (e >= 100 && e <= 140) hits++;
    }
    *flag = (hits >= 200) ? 1 : 0;
  }
}

// ---------------- CSR build ----------------
__global__ __launch_bounds__(256) void kc_hist(const int* __restrict__ dst,
                                               int* __restrict__ rowptr) {
  int e = blockIdx.x * 256 + threadIdx.x;
  if (e < NE) atomicAdd(rowptr + dst[e] + 1, 1);
}

// single-block inclusive scan of rowptr[1..NND]; rowptr[0] stays 0.
__global__ __launch_bounds__(1024) void kc_scan(int* __restrict__ rowptr) {
  __shared__ int sums[1024];
  const int t = threadIdx.x;
  const int CH = 49;                   // 1024*49 >= 50000
  int lo = 1 + t * CH;
  int hi = lo + CH; if (hi > NND + 1) hi = NND + 1;
  int local = 0;
  for (int i = lo; i < hi; ++i) local += rowptr[i];
  sums[t] = local;
  __syncthreads();
  for (int s = 1; s < 1024; s <<= 1) {
    int v = (t >= s) ? sums[t - s] : 0;
    __syncthreads();
    sums[t] += v;
    __syncthreads();
  }
  int running = sums[t] - local;       // exclusive prefix of this chunk
  for (int i = lo; i < hi; ++i) {
    running += rowptr[i];
    rowptr[i] = running;
  }
}

__global__ __launch_bounds__(256) void kc_scatter(const int* __restrict__ src,
                                                  const int* __restrict__ dst,
                                                  int* __restrict__ cursor,
                                                  int* __restrict__ col) {
  int e = blockIdx.x * 256 + threadIdx.x;
  if (e >= NE) return;
  int pos = atomicAdd(cursor + dst[e], 1);
  col[pos] = src[e];
}

// ---------------- K1: feat = h @ W[m] + el/er ----------------
template<int BF>
__global__ __launch_bounds__(256) void k1_gemm(
    const int* __restrict__ flag,
    const void* __restrict__ h, const void* __restrict__ W,
    const void* __restrict__ al, const void* __restrict__ ar,
    u16* __restrict__ feat, float* __restrict__ el, float* __restrict__ er,
    int m)
{
  if (*flag != BF) return;
  const int t = threadIdx.x;
  const int n0 = blockIdx.x * 16;
  const size_t wbase = (size_t)m * INF * HDIM;
  float acc[16];
#pragma unroll
  for (int i = 0; i < 16; ++i) acc[i] = 0.f;
  for (int k = 0; k < INF; ++k) {
    float w = ldf<BF>(W, wbase + (size_t)k * HDIM + t);
#pragma unroll
    for (int nn = 0; nn < 16; ++nn)
      acc[nn] = fmaf(ldf<BF>(h, (size_t)(n0 + nn) * INF + k), w, acc[nn]);
  }
  const int lane = t & 63;
  const int head = t >> 6;   // wave index == head (t = head*64 + d)
  const float alv = ldf<BF>(al, (size_t)m * HDIM + t);
  const float arv = ldf<BF>(ar, (size_t)m * HDIM + t);
#pragma unroll
  for (int nn = 0; nn < 16; ++nn) {
    float f = acc[nn];
    feat[(size_t)(n0 + nn) * HDIM + t] = f2us(f);
    float cl = f * alv;
    float cr = f * arv;
#pragma unroll
    for (int o = 32; o; o >>= 1) {
      cl += __shfl_xor(cl, o, 64);
      cr += __shfl_xor(cr, o, 64);
    }
    if (lane == 0) {
      el[(n0 + nn) * NH + head] = cl;
      er[(n0 + nn) * NH + head] = cr;
    }
  }
}

// ---------------- K3: CSR gather (fused den + aggregate + elu + z store) ----
// One wave per dst node; lane covers 4 contiguous feats (head = lane>>4).
template<int OBF>
__global__ __launch_bounds__(256) void k3_gather(
    const int* __restrict__ flag, int gate,
    const int* __restrict__ rowptr, const int* __restrict__ col,
    const float* __restrict__ el, const float* __restrict__ er,
    const u16* __restrict__ feat, void* __restrict__ z)
{
  if (gate >= 0 && *flag != gate) return;
  const int d = blockIdx.x * 4 + (threadIdx.x >> 6);
  if (d >= NND) return;
  const int lane = threadIdx.x & 63;
  const int h = lane >> 4;
  const int beg = rowptr[d], end = rowptr[d + 1];
  const float erh = er[d * 4 + h];
  float den = 0.f;
  for (int j = beg; j < end; ++j) {
    int s = col[j];
    float x = el[s * 4 + h] + erh;
    x = x > 0.f ? x : SLOPE * x;
    den += expf(x);
  }
  const float inv = 1.f / fmaxf(den, 1e-9f);
  float a0 = 0.f, a1 = 0.f, a2 = 0.f, a3 = 0.f;
  for (int j = beg; j < end; ++j) {
    int s = col[j];
    float x = el[s * 4 + h] + erh;
    x = x > 0.f ? x : SLOPE * x;
    float alpha = expf(x) * inv;
    const ushort4 f4 = *(const ushort4*)(feat + (size_t)s * HDIM + lane * 4);
    a0 = fmaf(alpha, us2f(f4.x), a0);
    a1 = fmaf(alpha, us2f(f4.y), a1);
    a2 = fmaf(alpha, us2f(f4.z), a2);
    a3 = fmaf(alpha, us2f(f4.w), a3);
  }
  // elu
  a0 = a0 > 0.f ? a0 : expf(a0) - 1.f;
  a1 = a1 > 0.f ? a1 : expf(a1) - 1.f;
  a2 = a2 > 0.f ? a2 : expf(a2) - 1.f;
  a3 = a3 > 0.f ? a3 : expf(a3) - 1.f;
  const size_t idx = (size_t)d * HDIM + lane * 4;
  if (OBF) {
    ushort4 r; r.x = f2us(a0); r.y = f2us(a1); r.z = f2us(a2); r.w = f2us(a3);
    *(ushort4*)((u16*)z + idx) = r;
  } else {
    float4 r; r.x = a0; r.y = a1; r.z = a2; r.w = a3;
    *(float4*)((float*)z + idx) = r;
  }
}

// ---------------- K4: semantic score accumulation (reads z) ----------------
template<int BF>
__global__ __launch_bounds__(256) void k4_sem(
    const int* __restrict__ flag,
    const void* __restrict__ z, const void* __restrict__ w1,
    const void* __restrict__ b1, const void* __restrict__ w2,
    float* __restrict__ wsum, int midx)
{
  if (*flag != BF) return;
  __shared__ float zl[2][HDIM];
  __shared__ float red[4];
  const int t = threadIdx.x;
  const int half = t >> 7;
  const int jj = t & 127;
  const int zisf32 = (midx == 0 && BF == 0);   // z0 lives in d_out (f32 path)
  const float b1f = ldf<BF>(b1, jj);
  const float w2f = ldf<BF>(w2, jj);
  float local = 0.f;
  for (int pp = 0; pp < 4; ++pp) {
    const int nbase = blockIdx.x * 8 + pp * 2;
    __syncthreads();
#pragma unroll
    for (int j = 0; j < 2; ++j) {
      const size_t idx = (size_t)(nbase + j) * HDIM + t;
      zl[j][t] = zisf32 ? ((const float*)z)[idx] : us2f(((const u16*)z)[idx]);
    }
    __syncthreads();
    float acc = 0.f;
    const float* zr = zl[half];
    for (int k = 0; k < HDIM; ++k)
      acc = fmaf(zr[k], ldf<BF>(w1, (size_t)k * SHID + jj), acc);
    local += tanhf(acc + b1f) * w2f;
  }
#pragma unroll
  for (int o = 32; o; o >>= 1) local += __shfl_xor(local, o, 64);
  const int lane = t & 63, wv = t >> 6;
  if (lane == 0) red[wv] = local;
  __syncthreads();
  if (t == 0) unsafeAtomicAdd(wsum + midx, red[0] + red[1] + red[2] + red[3]);
}

// ---------------- K5: out = b0*z0 + b1*z1 (z0 in d_out, in-place) ----------
template<int BF>
__global__ __launch_bounds__(256) void k5_out(
    const int* __restrict__ flag,
    void* __restrict__ out, const u16* __restrict__ z1,
    const float* __restrict__ wsum)
{
  if (*flag != BF) return;
  const int i = blockIdx.x * 256 + threadIdx.x;
  float w0 = wsum[0] * (1.0f / NND);
  float w1v = wsum[1] * (1.0f / NND);
  float mx = fmaxf(w0, w1v);
  float e0 = expf(w0 - mx), e1 = expf(w1v - mx);
  float inv = 1.f / (e0 + e1);
  float b0 = e0 * inv, b1 = e1 * inv;
  ushort4 zb = ((const ushort4*)z1)[i];
  if (BF) {
    ushort4 a = ((const ushort4*)out)[i];
    ushort4 r;
    r.x = f2us(b0 * us2f(a.x) + b1 * us2f(zb.x));
    r.y = f2us(b0 * us2f(a.y) + b1 * us2f(zb.y));
    r.z = f2us(b0 * us2f(a.z) + b1 * us2f(zb.z));
    r.w = f2us(b0 * us2f(a.w) + b1 * us2f(zb.w));
    ((ushort4*)out)[i] = r;
  } else {
    float4 a = ((const float4*)out)[i];
    float4 r;
    r.x = b0 * a.x + b1 * us2f(zb.x);
    r.y = b0 * a.y + b1 * us2f(zb.y);
    r.z = b0 * a.z + b1 * us2f(zb.z);
    r.w = b0 * a.w + b1 * us2f(zb.w);
    ((float4*)out)[i] = r;
  }
}

extern "C" void kernel_launch(void* const* d_in, const int* in_sizes, int n_in,
                              void* d_out, int out_size, void* d_ws, size_t ws_size,
                              hipStream_t stream)
{
  const int* src = (const int*)d_in[1];
  const int* dst = (const int*)d_in[2];

  // workspace layout (bytes)
  char* wsb = (char*)d_ws;
  u16*   feat   = (u16*)(wsb);                 // 25,600,000
  u16*   z1     = (u16*)(wsb + 25600000);      // 25,600,000
  int*   col    = (int*)(wsb + 51200000);      //  3,200,000
  float* el     = (float*)(wsb + 54400000);    //    800,000
  float* er     = (float*)(wsb + 55200000);    //    800,000
  int*   rowptr = (int*)(wsb + 56000000);      //    200,004
  int*   cursor = (int*)(wsb + 56200004);      //    200,000
  float* wsum   = (float*)(wsb + 56400004);    //          8
  int*   flag   = (int*)(wsb + 56400012);      //          4
  const size_t NEED = 56400016;
  if (ws_size < NEED) {
    hipMemsetAsync(d_out, 0x7F, (size_t)out_size * 2, stream);
    return;
  }

  k0_detect<<<1, 64, 0, stream>>>((const u16*)d_in[0], flag);
  hipMemsetAsync(wsum, 0, 2 * sizeof(float), stream);
  for (int m = 0; m < NM; ++m) {
    const int* src_m = src + (size_t)m * NE;
    const int* dst_m = dst + (size_t)m * NE;
    // CSR build
    hipMemsetAsync(rowptr, 0, (NND + 1) * sizeof(int), stream);
    kc_hist<<<NE / 256, 256, 0, stream>>>(dst_m, rowptr);
    kc_scan<<<1, 1024, 0, stream>>>(rowptr);
    hipMemcpyAsync(cursor, rowptr, NND * sizeof(int), hipMemcpyDeviceToDevice, stream);
    kc_scatter<<<NE / 256, 256, 0, stream>>>(src_m, dst_m, cursor, col);
    // GAT
    k1_gemm<0><<<NND / 16, 256, 0, stream>>>(flag, d_in[0], d_in[3], d_in[4], d_in[5], feat, el, er, m);
    k1_gemm<1><<<NND / 16, 256, 0, stream>>>(flag, d_in[0], d_in[3], d_in[4], d_in[5], feat, el, er, m);
    if (m == 0) {
      k3_gather<0><<<12500, 256, 0, stream>>>(flag, 0, rowptr, col, el, er, feat, d_out);
      k3_gather<1><<<12500, 256, 0, stream>>>(flag, 1, rowptr, col, el, er, feat, d_out);
    } else {
      k3_gather<1><<<12500, 256, 0, stream>>>(flag, -1, rowptr, col, el, er, feat, z1);
    }
    k4_sem<0><<<NND / 8, 256, 0, stream>>>(flag, (m == 0) ? d_out : (void*)z1, d_in[6], d_in[7], d_in[8], wsum, m);
    k4_sem<1><<<NND / 8, 256, 0, stream>>>(flag, (m == 0) ? d_out : (void*)z1, d_in[6], d_in[7], d_in[8], wsum, m);
  }
  k5_out<0><<<(NND * HDIM / 4) / 256, 256, 0, stream>>>(flag, d_out, z1, wsum);
  k5_out<1><<<(NND * HDIM / 4) / 256, 256, 0, stream>>>(flag, d_out, z1, wsum);
}